// Round 9
// baseline (220.323 us; speedup 1.0000x reference)
//
#include <hip/hip_runtime.h>
#include <hip/hip_bf16.h>
#include <float.h>
#include <limits.h>

#define NNODES 16384
#define KNB 8
#define HIDC 128
#define KNN_CAP 2528   // LDS candidate window (float4 = 40448 B) -> 4 blocks/CU

// -------- DPP helpers (pure-VALU cross-lane) --------
// wave-wide min of f32 (all values finite). Rotation-only DPP: no invalid lanes.
__device__ __forceinline__ float wave_min_f32(float x) {
  x = fminf(x, __int_as_float(__builtin_amdgcn_update_dpp(0, __float_as_int(x), 0xB1, 0xF, 0xF, true)));
  x = fminf(x, __int_as_float(__builtin_amdgcn_update_dpp(0, __float_as_int(x), 0x4E, 0xF, 0xF, true)));
  x = fminf(x, __int_as_float(__builtin_amdgcn_update_dpp(0, __float_as_int(x), 0x124, 0xF, 0xF, true)));
  x = fminf(x, __int_as_float(__builtin_amdgcn_update_dpp(0, __float_as_int(x), 0x128, 0xF, 0xF, true)));
  float r0 = __int_as_float(__builtin_amdgcn_readlane(__float_as_int(x), 0));
  float r1 = __int_as_float(__builtin_amdgcn_readlane(__float_as_int(x), 16));
  float r2 = __int_as_float(__builtin_amdgcn_readlane(__float_as_int(x), 32));
  float r3 = __int_as_float(__builtin_amdgcn_readlane(__float_as_int(x), 48));
  return fminf(fminf(r0, r1), fminf(r2, r3));
}

// sum across each 16-lane row (all lanes of the row end with the row sum).
// 4 DPP adds, no readlane, no cross-row traffic.
__device__ __forceinline__ float sum16(float x) {
  x += __int_as_float(__builtin_amdgcn_update_dpp(0, __float_as_int(x), 0xB1, 0xF, 0xF, true));  // quad xor1
  x += __int_as_float(__builtin_amdgcn_update_dpp(0, __float_as_int(x), 0x4E, 0xF, 0xF, true));  // quad xor2
  x += __int_as_float(__builtin_amdgcn_update_dpp(0, __float_as_int(x), 0x124, 0xF, 0xF, true)); // row_ror:4
  x += __int_as_float(__builtin_amdgcn_update_dpp(0, __float_as_int(x), 0x128, 0xF, 0xF, true)); // row_ror:8
  return x;
}

// squared distance — ONE formula everywhere so each (query,candidate) pair
// gets a single consistent rounding
__device__ __forceinline__ float dist2(float ax, float ay, float az,
                                       float bx, float by, float bz) {
  float dx = ax - bx, dy = ay - by, dz = az - bz;
  return fmaf(dz, dz, fmaf(dy, dy, dx * dx));
}

// Branchless sorted-insert of _d into ascending a0..a7 (v_med3_f32 per slot).
#define INS8V(_d, a0, a1, a2, a3, a4, a5, a6, a7)  \
  do {                                             \
    a7 = __builtin_amdgcn_fmed3f(_d, a6, a7);      \
    a6 = __builtin_amdgcn_fmed3f(_d, a5, a6);      \
    a5 = __builtin_amdgcn_fmed3f(_d, a4, a5);      \
    a4 = __builtin_amdgcn_fmed3f(_d, a3, a4);      \
    a3 = __builtin_amdgcn_fmed3f(_d, a2, a3);      \
    a2 = __builtin_amdgcn_fmed3f(_d, a1, a2);      \
    a1 = __builtin_amdgcn_fmed3f(_d, a0, a1);      \
    a0 = fminf(a0, _d);                            \
  } while (0)

// pop 8 wave-wide minima from the distributed lists; returns the 8th smallest
__device__ __forceinline__ float merge_T(float l0, float l1, float l2, float l3,
                                         float l4, float l5, float l6, float l7,
                                         int lane) {
  float T = 0.f;
  #pragma unroll
  for (int r = 0; r < KNB; ++r) {
    float m = wave_min_f32(l0);
    T = m;
    unsigned long long msk = __ballot(l0 == m);
    int p = (int)__builtin_ctzll(msk);
    if (lane == p) { l0 = l1; l1 = l2; l2 = l3; l3 = l4; l4 = l5; l5 = l6; l6 = l7; l7 = FLT_MAX; }
  }
  return T;
}

// slow path: exact single-query KNN over a global range (rare: graph straddle
// or window overflow). Whole wave participates.
__device__ void knn_global_single(const float* __restrict__ coord,
                                  float qx, float qy, float qz,
                                  int s, int e, int lane,
                                  int* __restrict__ knn_row) {
  float l0 = FLT_MAX, l1 = FLT_MAX, l2 = FLT_MAX, l3 = FLT_MAX,
        l4 = FLT_MAX, l5 = FLT_MAX, l6 = FLT_MAX, l7 = FLT_MAX;
  for (int base = s; base < e; base += 64) {
    int j = base + lane;
    bool ok = j < e;
    int jc = ok ? j : s;
    float d = dist2(coord[jc*3+0], coord[jc*3+1], coord[jc*3+2], qx, qy, qz);
    d = ok ? d : FLT_MAX;
    INS8V(d, l0, l1, l2, l3, l4, l5, l6, l7);
  }
  float T = merge_T(l0, l1, l2, l3, l4, l5, l6, l7, lane);
  unsigned long long lt = (1ull << lane) - 1ull;
  int cnt = 0;
  for (int base = s; base < e; base += 64) {
    int j = base + lane;
    bool ok = j < e;
    int jc = ok ? j : s;
    float d = dist2(coord[jc*3+0], coord[jc*3+1], coord[jc*3+2], qx, qy, qz);
    bool win = ok && (d <= T);
    unsigned long long msk = __ballot(win);
    if (msk) {
      int slot = cnt + __popcll(msk & lt);
      if (win && slot < KNB) knn_row[slot] = j;
      cnt += __popcll(msk);
    }
  }
}

// ---------------- segment table: seg[b] = lower_bound(batch, b), b in [0,8] ----------------
__global__ void seg_kernel(const int* __restrict__ batch, int* __restrict__ seg) {
  int b = threadIdx.x;
  if (b > 8) return;
  int lo = 0, hi = NNODES;
  while (lo < hi) { int m = (lo + hi) >> 1; if (batch[m] < b) lo = m + 1; else hi = m; }
  seg[b] = lo;
}

// ---------------- KNN (+ fused layer-0 linear) ----------------
// Block = 512 threads (8 waves) = 16 consecutive query nodes sharing one LDS
// candidate window; each wave handles TWO queries. Both passes issue FOUR
// independent ds_read_b128 per iteration (r4-proven MLP pattern: intra-wave
// load overlap is what keeps VALUBusy ~80%).
__global__ __launch_bounds__(512, 8) void knnlin_kernel(
    const float* __restrict__ coord, const int* __restrict__ batch,
    const float* __restrict__ feat,
    const float* __restrict__ Wl0, const float* __restrict__ bl0,
    const float* __restrict__ Wr0, const float* __restrict__ br0,
    const int* __restrict__ seg,
    int* __restrict__ knn, float* __restrict__ xl, float* __restrict__ xr) {
  __shared__ float4 tile[KNN_CAP];
  int t = threadIdx.x;
  int lane = t & 63;
  int wid = t >> 6;
  int n0 = blockIdx.x * 16;

  int b0 = batch[n0];
  int blast = batch[n0 + 15];
  int smin = seg[b0];
  int emax = seg[blast + 1];
  int win_end = min(emax, smin + KNN_CAP);
  int cnt_fill = win_end - smin;

  // cooperative fill of candidate window
  for (int i = t; i < cnt_fill; i += 512) {
    const float* cp = coord + (size_t)(smin + i) * 3;
    tile[i] = make_float4(cp[0], cp[1], cp[2], 0.f);
  }
  __syncthreads();

  int nA = n0 + wid * 2, nB = nA + 1;
  int bA = batch[nA], bB = batch[nB];
  int sA = seg[bA], eA = seg[bA + 1];
  bool fast = (bA == bB) && (eA - smin <= KNN_CAP);

  float ax = coord[nA*3+0], ay = coord[nA*3+1], az = coord[nA*3+2];
  float bx = coord[nB*3+0], by = coord[nB*3+1], bz = coord[nB*3+2];

  if (fast) {
    int lo_i = sA - smin;
    int M = eA - sA;
    int F4 = M >> 8;              // groups of 256 candidates

    // ---- pass 1: 4 independent LDS loads/iter, branchless top-8 both queries ----
    float a0 = FLT_MAX, a1 = FLT_MAX, a2 = FLT_MAX, a3 = FLT_MAX,
          a4 = FLT_MAX, a5 = FLT_MAX, a6 = FLT_MAX, a7 = FLT_MAX;
    float b0r = FLT_MAX, b1 = FLT_MAX, b2 = FLT_MAX, b3 = FLT_MAX,
          b4 = FLT_MAX, b5 = FLT_MAX, b6 = FLT_MAX, b7 = FLT_MAX;
    {
      const float4* tl = tile + lo_i;
      for (int it = 0; it < F4; ++it) {
        float4 c0 = tl[lane];
        float4 c1 = tl[lane + 64];
        float4 c2 = tl[lane + 128];
        float4 c3 = tl[lane + 192];
        tl += 256;
        float dA0 = dist2(c0.x, c0.y, c0.z, ax, ay, az);
        float dB0 = dist2(c0.x, c0.y, c0.z, bx, by, bz);
        float dA1 = dist2(c1.x, c1.y, c1.z, ax, ay, az);
        float dB1 = dist2(c1.x, c1.y, c1.z, bx, by, bz);
        float dA2 = dist2(c2.x, c2.y, c2.z, ax, ay, az);
        float dB2 = dist2(c2.x, c2.y, c2.z, bx, by, bz);
        float dA3 = dist2(c3.x, c3.y, c3.z, ax, ay, az);
        float dB3 = dist2(c3.x, c3.y, c3.z, bx, by, bz);
        INS8V(dA0, a0, a1, a2, a3, a4, a5, a6, a7);
        INS8V(dB0, b0r, b1, b2, b3, b4, b5, b6, b7);
        INS8V(dA1, a0, a1, a2, a3, a4, a5, a6, a7);
        INS8V(dB1, b0r, b1, b2, b3, b4, b5, b6, b7);
        INS8V(dA2, a0, a1, a2, a3, a4, a5, a6, a7);
        INS8V(dB2, b0r, b1, b2, b3, b4, b5, b6, b7);
        INS8V(dA3, a0, a1, a2, a3, a4, a5, a6, a7);
        INS8V(dB3, b0r, b1, b2, b3, b4, b5, b6, b7);
      }
      for (int base = F4 << 8; base < M; base += 64) {
        int lix = base + lane;
        bool ok = lix < M;
        float4 c = tile[ok ? (lo_i + lix) : lo_i];
        float dA = dist2(c.x, c.y, c.z, ax, ay, az);
        float dB = dist2(c.x, c.y, c.z, bx, by, bz);
        dA = ok ? dA : FLT_MAX;
        dB = ok ? dB : FLT_MAX;
        INS8V(dA, a0, a1, a2, a3, a4, a5, a6, a7);
        INS8V(dB, b0r, b1, b2, b3, b4, b5, b6, b7);
      }
    }

    // ---- merge: exact 8th-smallest per query ----
    float TA = merge_T(a0, a1, a2, a3, a4, a5, a6, a7, lane);
    float TB = merge_T(b0r, b1, b2, b3, b4, b5, b6, b7, lane);

    // ---- pass 2: collect first-8-by-index with d <= T (order-free downstream;
    //      lowest-index tie policy matches stable top_k) ----
    unsigned long long lt = (1ull << lane) - 1ull;
    int cntA = 0, cntB = 0;
    {
      const float4* t2 = tile + lo_i;
      for (int it = 0; it < F4 && (cntA < KNB || cntB < KNB); ++it) {
        float4 c0 = t2[lane];
        float4 c1 = t2[lane + 64];
        float4 c2 = t2[lane + 128];
        float4 c3 = t2[lane + 192];
        t2 += 256;
        int g0 = sA + (it << 8) + lane;
        #pragma unroll
        for (int q = 0; q < 4; ++q) {
          float4 c = (q == 0) ? c0 : (q == 1) ? c1 : (q == 2) ? c2 : c3;
          int gidx = g0 + (q << 6);
          float dA = dist2(c.x, c.y, c.z, ax, ay, az);
          float dB = dist2(c.x, c.y, c.z, bx, by, bz);
          unsigned long long mA = __ballot(dA <= TA);
          if (mA) {
            int slot = cntA + __popcll(mA & lt);
            if ((dA <= TA) && slot < KNB) knn[nA*KNB + slot] = gidx;
            cntA += __popcll(mA);
          }
          unsigned long long mB = __ballot(dB <= TB);
          if (mB) {
            int slot = cntB + __popcll(mB & lt);
            if ((dB <= TB) && slot < KNB) knn[nB*KNB + slot] = gidx;
            cntB += __popcll(mB);
          }
        }
      }
      for (int base = F4 << 8; base < M && (cntA < KNB || cntB < KNB); base += 64) {
        int lix = base + lane;
        bool ok = lix < M;
        float4 c = tile[ok ? (lo_i + lix) : lo_i];
        float dA = dist2(c.x, c.y, c.z, ax, ay, az);
        float dB = dist2(c.x, c.y, c.z, bx, by, bz);
        int gidx = sA + lix;
        bool wA = ok && (dA <= TA);
        bool wB = ok && (dB <= TB);
        unsigned long long mA = __ballot(wA);
        if (mA) {
          int slot = cntA + __popcll(mA & lt);
          if (wA && slot < KNB) knn[nA*KNB + slot] = gidx;
          cntA += __popcll(mA);
        }
        unsigned long long mB = __ballot(wB);
        if (mB) {
          int slot = cntB + __popcll(mB & lt);
          if (wB && slot < KNB) knn[nB*KNB + slot] = gidx;
          cntB += __popcll(mB);
        }
      }
    }
  } else {
    // rare: graph straddle / window overflow — global exact scan per query
    int sB2 = seg[bB], eB2 = seg[bB + 1];
    knn_global_single(coord, ax, ay, az, sA, eA, lane, knn + (size_t)nA * KNB);
    knn_global_single(coord, bx, by, bz, sB2, eB2, lane, knn + (size_t)nB * KNB);
  }

  // ---- fused layer-0 linear: xl/xr = feat @ Wl0/Wr0 + b for this block's 16 nodes ----
  {
    int cg = t & 63;                 // 64 col-groups of 4 (0..31 -> xl, 32..63 -> xr)
    bool isR = cg >= 32;
    const float* W  = isR ? Wr0 : Wl0;
    const float* bi = isR ? br0 : bl0;
    float* dst      = isR ? xr : xl;
    int wc = (cg & 31) * 4;
    float4 w0 = *(const float4*)(W + 0 * HIDC + wc);
    float4 w1 = *(const float4*)(W + 1 * HIDC + wc);
    float4 w2 = *(const float4*)(W + 2 * HIDC + wc);
    float4 w3 = *(const float4*)(W + 3 * HIDC + wc);
    float4 w4 = *(const float4*)(W + 4 * HIDC + wc);
    float4 w5 = *(const float4*)(W + 5 * HIDC + wc);
    float4 bb = *(const float4*)(bi + wc);
    #pragma unroll
    for (int s2 = 0; s2 < 2; ++s2) {
      int node = n0 + wid * 2 + s2;
      const float* fr = feat + (size_t)node * 6;
      float f0 = fr[0], f1 = fr[1], f2 = fr[2], f3 = fr[3], f4 = fr[4], f5 = fr[5];
      float4 acc = make_float4(0.f, 0.f, 0.f, 0.f);
      acc.x = fmaf(f0, w0.x, acc.x); acc.y = fmaf(f0, w0.y, acc.y);
      acc.z = fmaf(f0, w0.z, acc.z); acc.w = fmaf(f0, w0.w, acc.w);
      acc.x = fmaf(f1, w1.x, acc.x); acc.y = fmaf(f1, w1.y, acc.y);
      acc.z = fmaf(f1, w1.z, acc.z); acc.w = fmaf(f1, w1.w, acc.w);
      acc.x = fmaf(f2, w2.x, acc.x); acc.y = fmaf(f2, w2.y, acc.y);
      acc.z = fmaf(f2, w2.z, acc.z); acc.w = fmaf(f2, w2.w, acc.w);
      acc.x = fmaf(f3, w3.x, acc.x); acc.y = fmaf(f3, w3.y, acc.y);
      acc.z = fmaf(f3, w3.z, acc.z); acc.w = fmaf(f3, w3.w, acc.w);
      acc.x = fmaf(f4, w4.x, acc.x); acc.y = fmaf(f4, w4.y, acc.y);
      acc.z = fmaf(f4, w4.z, acc.z); acc.w = fmaf(f4, w4.w, acc.w);
      acc.x = fmaf(f5, w5.x, acc.x); acc.y = fmaf(f5, w5.y, acc.y);
      acc.z = fmaf(f5, w5.z, acc.z); acc.w = fmaf(f5, w5.w, acc.w);
      float4 o;
      o.x = acc.x + bb.x; o.y = acc.y + bb.y;
      o.z = acc.z + bb.z; o.w = acc.w + bb.w;
      *(float4*)(dst + (size_t)node * HIDC + wc) = o;
    }
  }
}

// ---------------- xl = x@Wl + bl ; xr = x@Wr + br  (16-node tiles) ----------
__global__ __launch_bounds__(256, 8) void lin2_kernel(
    const float* __restrict__ x,
    const float* __restrict__ Wl, const float* __restrict__ bl,
    const float* __restrict__ Wr, const float* __restrict__ br,
    float* __restrict__ xl, float* __restrict__ xr) {
  __shared__ float xs[16 * HIDC];
  int t = threadIdx.x;
  int node0 = blockIdx.x * 16;
  for (int i = t; i < 16 * HIDC; i += 256) xs[i] = x[node0 * HIDC + i];
  __syncthreads();
  int cg = t & 63;        // 64 col-groups x 4 cols = 256 combined cols
  int ng = t >> 6;        // 4 node-groups x 4 nodes
  int c0 = cg * 4;
  bool isR = (c0 >= HIDC);
  const float* W    = isR ? Wr : Wl;
  const float* bias = isR ? br : bl;
  float* dst        = isR ? xr : xl;
  int wc = isR ? (c0 - HIDC) : c0;

  float4 acc[4];
  #pragma unroll
  for (int nn = 0; nn < 4; ++nn) acc[nn] = make_float4(0.f, 0.f, 0.f, 0.f);

  for (int k0 = 0; k0 < HIDC; k0 += 4) {
    float4 xv[4];
    #pragma unroll
    for (int nn = 0; nn < 4; ++nn)
      xv[nn] = *(const float4*)&xs[(ng * 4 + nn) * HIDC + k0];  // uniform-addr broadcast
    #pragma unroll
    for (int q = 0; q < 4; ++q) {
      float4 w = *(const float4*)(W + (size_t)(k0 + q) * HIDC + wc);
      #pragma unroll
      for (int nn = 0; nn < 4; ++nn) {
        float xq = (q == 0) ? xv[nn].x : (q == 1) ? xv[nn].y : (q == 2) ? xv[nn].z : xv[nn].w;
        acc[nn].x = fmaf(xq, w.x, acc[nn].x);
        acc[nn].y = fmaf(xq, w.y, acc[nn].y);
        acc[nn].z = fmaf(xq, w.z, acc[nn].z);
        acc[nn].w = fmaf(xq, w.w, acc[nn].w);
      }
    }
  }
  float4 b4 = *(const float4*)(bias + wc);
  #pragma unroll
  for (int nn = 0; nn < 4; ++nn) {
    int node = node0 + ng * 4 + nn;
    float4 o;
    o.x = acc[nn].x + b4.x; o.y = acc[nn].y + b4.y;
    o.z = acc[nn].z + b4.z; o.w = acc[nn].w + b4.w;
    *(float4*)(dst + (size_t)node * HIDC + wc) = o;
  }
}

// -------- GATv2 attention + aggregate + bias + relu --------
// 16 lanes per node (8 channels/lane), 4 nodes/wave, 16 nodes/block.
// Logit reduce = 4 DPP row-ops (sum16) — no readlane, no cross-row, softmax
// is lane-uniform. Two-pass neighbor gather (2nd pass L1/L2-hot).
template<bool FINAL>
__global__ __launch_bounds__(256, 8) void gat_attn_kernel(
    const float* __restrict__ xl, const float* __restrict__ xr,
    const int* __restrict__ knn, const float* __restrict__ att,
    const float* __restrict__ bias, float* __restrict__ xout,
    const float* __restrict__ Wf, const float* __restrict__ bf,
    float* __restrict__ out) {
  int t = threadIdx.x;
  int li = t & 15;                 // lane within node group (DPP row)
  int grp = t >> 4;                // 16 node-groups per block
  int n = blockIdx.x * 16 + grp;
  int c0 = li * 8;

  float4 xr0 = *(const float4*)(xr + (size_t)n * HIDC + c0);
  float4 xr1 = *(const float4*)(xr + (size_t)n * HIDC + c0 + 4);
  float4 at0 = *(const float4*)(att + c0);
  float4 at1 = *(const float4*)(att + c0 + 4);
  int4 j0 = *(const int4*)(knn + (size_t)n * KNB);
  int4 j1 = *(const int4*)(knn + (size_t)n * KNB + 4);

  // ---- pass 1: logits ----
  float lg[8];
  #pragma unroll
  for (int k = 0; k < 8; ++k) {
    int j = (k==0)?j0.x:(k==1)?j0.y:(k==2)?j0.z:(k==3)?j0.w
          :(k==4)?j1.x:(k==5)?j1.y:(k==6)?j1.z:j1.w;
    float4 g0 = *(const float4*)(xl + (size_t)j * HIDC + c0);
    float4 g1 = *(const float4*)(xl + (size_t)j * HIDC + c0 + 4);
    float e, p;
    e = g0.x + xr0.x; e = e > 0.f ? e : 0.2f * e; p = e * at0.x;
    e = g0.y + xr0.y; e = e > 0.f ? e : 0.2f * e; p = fmaf(e, at0.y, p);
    e = g0.z + xr0.z; e = e > 0.f ? e : 0.2f * e; p = fmaf(e, at0.z, p);
    e = g0.w + xr0.w; e = e > 0.f ? e : 0.2f * e; p = fmaf(e, at0.w, p);
    e = g1.x + xr1.x; e = e > 0.f ? e : 0.2f * e; p = fmaf(e, at1.x, p);
    e = g1.y + xr1.y; e = e > 0.f ? e : 0.2f * e; p = fmaf(e, at1.y, p);
    e = g1.z + xr1.z; e = e > 0.f ? e : 0.2f * e; p = fmaf(e, at1.z, p);
    e = g1.w + xr1.w; e = e > 0.f ? e : 0.2f * e; p = fmaf(e, at1.w, p);
    lg[k] = sum16(p);
  }

  // ---- softmax over k (lane-uniform within the group) ----
  float mx = lg[0];
  #pragma unroll
  for (int k = 1; k < 8; ++k) mx = fmaxf(mx, lg[k]);
  float ssum = 0.f;
  #pragma unroll
  for (int k = 0; k < 8; ++k) { lg[k] = __expf(lg[k] - mx); ssum += lg[k]; }
  float inv = 1.f / ssum;

  // ---- pass 2: weighted aggregate (re-gather, cache-hot) ----
  float4 o0 = make_float4(0.f, 0.f, 0.f, 0.f);
  float4 o1 = make_float4(0.f, 0.f, 0.f, 0.f);
  #pragma unroll
  for (int k = 0; k < 8; ++k) {
    int j = (k==0)?j0.x:(k==1)?j0.y:(k==2)?j0.z:(k==3)?j0.w
          :(k==4)?j1.x:(k==5)?j1.y:(k==6)?j1.z:j1.w;
    float wk = lg[k];
    float4 g0 = *(const float4*)(xl + (size_t)j * HIDC + c0);
    float4 g1 = *(const float4*)(xl + (size_t)j * HIDC + c0 + 4);
    o0.x = fmaf(wk, g0.x, o0.x); o0.y = fmaf(wk, g0.y, o0.y);
    o0.z = fmaf(wk, g0.z, o0.z); o0.w = fmaf(wk, g0.w, o0.w);
    o1.x = fmaf(wk, g1.x, o1.x); o1.y = fmaf(wk, g1.y, o1.y);
    o1.z = fmaf(wk, g1.z, o1.z); o1.w = fmaf(wk, g1.w, o1.w);
  }
  float4 b0 = *(const float4*)(bias + c0);
  float4 b1 = *(const float4*)(bias + c0 + 4);
  o0.x = fmaxf(fmaf(o0.x, inv, b0.x), 0.f);
  o0.y = fmaxf(fmaf(o0.y, inv, b0.y), 0.f);
  o0.z = fmaxf(fmaf(o0.z, inv, b0.z), 0.f);
  o0.w = fmaxf(fmaf(o0.w, inv, b0.w), 0.f);
  o1.x = fmaxf(fmaf(o1.x, inv, b1.x), 0.f);
  o1.y = fmaxf(fmaf(o1.y, inv, b1.y), 0.f);
  o1.z = fmaxf(fmaf(o1.z, inv, b1.z), 0.f);
  o1.w = fmaxf(fmaf(o1.w, inv, b1.w), 0.f);

  if (!FINAL) {
    *(float4*)(xout + (size_t)n * HIDC + c0) = o0;
    *(float4*)(xout + (size_t)n * HIDC + c0 + 4) = o1;
  } else {
    const float* wf = Wf + (size_t)c0 * 3;
    float p0, p1, p2;
    p0 = o0.x * wf[0];            p1 = o0.x * wf[1];            p2 = o0.x * wf[2];
    p0 = fmaf(o0.y, wf[3], p0);   p1 = fmaf(o0.y, wf[4], p1);   p2 = fmaf(o0.y, wf[5], p2);
    p0 = fmaf(o0.z, wf[6], p0);   p1 = fmaf(o0.z, wf[7], p1);   p2 = fmaf(o0.z, wf[8], p2);
    p0 = fmaf(o0.w, wf[9], p0);   p1 = fmaf(o0.w, wf[10], p1);  p2 = fmaf(o0.w, wf[11], p2);
    p0 = fmaf(o1.x, wf[12], p0);  p1 = fmaf(o1.x, wf[13], p1);  p2 = fmaf(o1.x, wf[14], p2);
    p0 = fmaf(o1.y, wf[15], p0);  p1 = fmaf(o1.y, wf[16], p1);  p2 = fmaf(o1.y, wf[17], p2);
    p0 = fmaf(o1.z, wf[18], p0);  p1 = fmaf(o1.z, wf[19], p1);  p2 = fmaf(o1.z, wf[20], p2);
    p0 = fmaf(o1.w, wf[21], p0);  p1 = fmaf(o1.w, wf[22], p1);  p2 = fmaf(o1.w, wf[23], p2);
    p0 = sum16(p0);
    p1 = sum16(p1);
    p2 = sum16(p2);
    if (li < 3) {
      float pv = (li == 0) ? p0 : (li == 1) ? p1 : p2;
      out[(size_t)n * 3 + li] = pv + bf[li];
    }
  }
}

extern "C" void kernel_launch(void* const* d_in, const int* in_sizes, int n_in,
                              void* d_out, int out_size, void* d_ws, size_t ws_size,
                              hipStream_t stream) {
  const float* coord = (const float*)d_in[0];
  const float* feat  = (const float*)d_in[1];
  const int*   batch = (const int*)d_in[2];
  const float* Wl0 = (const float*)d_in[3];
  const float* bl0 = (const float*)d_in[4];
  const float* Wr0 = (const float*)d_in[5];
  const float* br0 = (const float*)d_in[6];
  const float* att0  = (const float*)d_in[7];
  const float* bias0 = (const float*)d_in[8];
  const float* Wl1 = (const float*)d_in[9];
  const float* bl1 = (const float*)d_in[10];
  const float* Wr1 = (const float*)d_in[11];
  const float* br1 = (const float*)d_in[12];
  const float* att1  = (const float*)d_in[13];
  const float* bias1 = (const float*)d_in[14];
  const float* Wl2 = (const float*)d_in[15];
  const float* bl2 = (const float*)d_in[16];
  const float* Wr2 = (const float*)d_in[17];
  const float* br2 = (const float*)d_in[18];
  const float* att2  = (const float*)d_in[19];
  const float* bias2 = (const float*)d_in[20];
  const float* Wf = (const float*)d_in[21];
  const float* bf = (const float*)d_in[22];
  float* out = (float*)d_out;

  char* ws = (char*)d_ws;
  int*   knn = (int*)ws;                                   // 512 KB
  float* xl  = (float*)(ws + (512 << 10));                 // 8 MB
  float* xr  = xl + (size_t)NNODES * HIDC;                 // 8 MB
  float* xb0 = xr + (size_t)NNODES * HIDC;                 // 8 MB
  float* xb1 = xb0 + (size_t)NNODES * HIDC;                // 8 MB
  int*   seg = (int*)xb1;  // 9 ints; xb1 not live until gat1 writes it

  seg_kernel<<<1, 16, 0, stream>>>(batch, seg);
  knnlin_kernel<<<NNODES / 16, 512, 0, stream>>>(coord, batch, feat,
                                                 Wl0, bl0, Wr0, br0, seg, knn, xl, xr);
  gat_attn_kernel<false><<<NNODES / 16, 256, 0, stream>>>(xl, xr, knn, att0, bias0, xb0,
                                                          nullptr, nullptr, nullptr);

  lin2_kernel<<<NNODES / 16, 256, 0, stream>>>(xb0, Wl1, bl1, Wr1, br1, xl, xr);
  gat_attn_kernel<false><<<NNODES / 16, 256, 0, stream>>>(xl, xr, knn, att1, bias1, xb1,
                                                          nullptr, nullptr, nullptr);

  lin2_kernel<<<NNODES / 16, 256, 0, stream>>>(xb1, Wl2, bl2, Wr2, br2, xl, xr);
  gat_attn_kernel<true><<<NNODES / 16, 256, 0, stream>>>(xl, xr, knn, att2, bias2, nullptr,
                                                         Wf, bf, out);
}

// Round 10
// 138.064 us; speedup vs baseline: 1.5958x; 1.5958x over previous
//
#include <hip/hip_runtime.h>
#include <hip/hip_bf16.h>
#include <float.h>
#include <limits.h>

#define NNODES 16384
#define KNB 8
#define HIDC 128
#define KNN_CAP 2528   // SoA LDS window: 3 * 2528 * 4B = 30336 B -> LDS no longer caps occupancy

// -------- DPP helpers (pure-VALU cross-lane) --------
__device__ __forceinline__ float wave_sum(float x) {
  x += __int_as_float(__builtin_amdgcn_update_dpp(0, __float_as_int(x), 0xB1, 0xF, 0xF, true));  // quad xor1
  x += __int_as_float(__builtin_amdgcn_update_dpp(0, __float_as_int(x), 0x4E, 0xF, 0xF, true));  // quad xor2
  x += __int_as_float(__builtin_amdgcn_update_dpp(0, __float_as_int(x), 0x124, 0xF, 0xF, true)); // row_ror:4
  x += __int_as_float(__builtin_amdgcn_update_dpp(0, __float_as_int(x), 0x128, 0xF, 0xF, true)); // row_ror:8
  float r0 = __int_as_float(__builtin_amdgcn_readlane(__float_as_int(x), 0));
  float r1 = __int_as_float(__builtin_amdgcn_readlane(__float_as_int(x), 16));
  float r2 = __int_as_float(__builtin_amdgcn_readlane(__float_as_int(x), 32));
  float r3 = __int_as_float(__builtin_amdgcn_readlane(__float_as_int(x), 48));
  return (r0 + r1) + (r2 + r3);
}

// wave-wide min of f32 (all values finite). Rotation-only DPP: no invalid lanes.
__device__ __forceinline__ float wave_min_f32(float x) {
  x = fminf(x, __int_as_float(__builtin_amdgcn_update_dpp(0, __float_as_int(x), 0xB1, 0xF, 0xF, true)));
  x = fminf(x, __int_as_float(__builtin_amdgcn_update_dpp(0, __float_as_int(x), 0x4E, 0xF, 0xF, true)));
  x = fminf(x, __int_as_float(__builtin_amdgcn_update_dpp(0, __float_as_int(x), 0x124, 0xF, 0xF, true)));
  x = fminf(x, __int_as_float(__builtin_amdgcn_update_dpp(0, __float_as_int(x), 0x128, 0xF, 0xF, true)));
  float r0 = __int_as_float(__builtin_amdgcn_readlane(__float_as_int(x), 0));
  float r1 = __int_as_float(__builtin_amdgcn_readlane(__float_as_int(x), 16));
  float r2 = __int_as_float(__builtin_amdgcn_readlane(__float_as_int(x), 32));
  float r3 = __int_as_float(__builtin_amdgcn_readlane(__float_as_int(x), 48));
  return fminf(fminf(r0, r1), fminf(r2, r3));
}

// squared distance — ONE formula everywhere so each (query,candidate) pair
// gets a single consistent rounding
__device__ __forceinline__ float dist2(float ax, float ay, float az,
                                       float bx, float by, float bz) {
  float dx = ax - bx, dy = ay - by, dz = az - bz;
  return fmaf(dz, dz, fmaf(dy, dy, dx * dx));
}

// Branchless sorted-insert of _d into ascending a0..a7 (v_med3_f32 per slot).
#define INS8V(_d, a0, a1, a2, a3, a4, a5, a6, a7)  \
  do {                                             \
    a7 = __builtin_amdgcn_fmed3f(_d, a6, a7);      \
    a6 = __builtin_amdgcn_fmed3f(_d, a5, a6);      \
    a5 = __builtin_amdgcn_fmed3f(_d, a4, a5);      \
    a4 = __builtin_amdgcn_fmed3f(_d, a3, a4);      \
    a3 = __builtin_amdgcn_fmed3f(_d, a2, a3);      \
    a2 = __builtin_amdgcn_fmed3f(_d, a1, a2);      \
    a1 = __builtin_amdgcn_fmed3f(_d, a0, a1);      \
    a0 = fminf(a0, _d);                            \
  } while (0)

// pop 8 wave-wide minima from the distributed lists; returns the 8th smallest
__device__ __forceinline__ float merge_T(float l0, float l1, float l2, float l3,
                                         float l4, float l5, float l6, float l7,
                                         int lane) {
  float T = 0.f;
  #pragma unroll
  for (int r = 0; r < KNB; ++r) {
    float m = wave_min_f32(l0);
    T = m;
    unsigned long long msk = __ballot(l0 == m);
    int p = (int)__builtin_ctzll(msk);
    if (lane == p) { l0 = l1; l1 = l2; l2 = l3; l3 = l4; l4 = l5; l5 = l6; l6 = l7; l7 = FLT_MAX; }
  }
  return T;
}

// slow path: exact single-query KNN over a global range (rare: graph straddle
// or window overflow). Whole wave participates.
__device__ void knn_global_single(const float* __restrict__ coord,
                                  float qx, float qy, float qz,
                                  int s, int e, int lane,
                                  int* __restrict__ knn_row) {
  float l0 = FLT_MAX, l1 = FLT_MAX, l2 = FLT_MAX, l3 = FLT_MAX,
        l4 = FLT_MAX, l5 = FLT_MAX, l6 = FLT_MAX, l7 = FLT_MAX;
  for (int base = s; base < e; base += 64) {
    int j = base + lane;
    bool ok = j < e;
    int jc = ok ? j : s;
    float d = dist2(coord[jc*3+0], coord[jc*3+1], coord[jc*3+2], qx, qy, qz);
    d = ok ? d : FLT_MAX;
    INS8V(d, l0, l1, l2, l3, l4, l5, l6, l7);
  }
  float T = merge_T(l0, l1, l2, l3, l4, l5, l6, l7, lane);
  unsigned long long lt = (1ull << lane) - 1ull;
  int cnt = 0;
  for (int base = s; base < e; base += 64) {
    int j = base + lane;
    bool ok = j < e;
    int jc = ok ? j : s;
    float d = dist2(coord[jc*3+0], coord[jc*3+1], coord[jc*3+2], qx, qy, qz);
    bool win = ok && (d <= T);
    unsigned long long msk = __ballot(win);
    if (msk) {
      int slot = cnt + __popcll(msk & lt);
      if (win && slot < KNB) knn_row[slot] = j;
      cnt += __popcll(msk);
    }
  }
}

// ---------------- segment table: seg[b] = lower_bound(batch, b), b in [0,8] ----------------
__global__ void seg_kernel(const int* __restrict__ batch, int* __restrict__ seg) {
  int b = threadIdx.x;
  if (b > 8) return;
  int lo = 0, hi = NNODES;
  while (lo < hi) { int m = (lo + hi) >> 1; if (batch[m] < b) lo = m + 1; else hi = m; }
  seg[b] = lo;
}

// ---------------- KNN (+ fused layer-0 linear) ----------------
// Block = 512 threads (8 waves) = 16 consecutive query nodes; SoA LDS window
// (30.3 KB -> 4 blocks/CU, 32 waves/CU = 8 waves/SIMD: TLP hides LDS latency).
// Each wave handles TWO queries (one tile read serves both).
__global__ __launch_bounds__(512, 8) void knnlin_kernel(
    const float* __restrict__ coord, const int* __restrict__ batch,
    const float* __restrict__ feat,
    const float* __restrict__ Wl0, const float* __restrict__ bl0,
    const float* __restrict__ Wr0, const float* __restrict__ br0,
    const int* __restrict__ seg,
    int* __restrict__ knn, float* __restrict__ xl, float* __restrict__ xr) {
  __shared__ float xs[KNN_CAP];
  __shared__ float ys[KNN_CAP];
  __shared__ float zs[KNN_CAP];
  int t = threadIdx.x;
  int lane = t & 63;
  int wid = t >> 6;
  int n0 = blockIdx.x * 16;

  int b0 = batch[n0];
  int blast = batch[n0 + 15];
  int smin = seg[b0];
  int emax = seg[blast + 1];
  int win_end = min(emax, smin + KNN_CAP);
  int cnt_fill = win_end - smin;

  // cooperative fill of candidate window (SoA)
  for (int i = t; i < cnt_fill; i += 512) {
    const float* cp = coord + (size_t)(smin + i) * 3;
    xs[i] = cp[0]; ys[i] = cp[1]; zs[i] = cp[2];
  }
  __syncthreads();

  int nA = n0 + wid * 2, nB = nA + 1;
  int bA = batch[nA], bB = batch[nB];
  int sA = seg[bA], eA = seg[bA + 1];
  bool fast = (bA == bB) && (eA - smin <= KNN_CAP);

  float ax = coord[nA*3+0], ay = coord[nA*3+1], az = coord[nA*3+2];
  float bx = coord[nB*3+0], by = coord[nB*3+1], bz = coord[nB*3+2];

  if (fast) {
    int lo_i = sA - smin;
    int M = eA - sA;
    int F4 = M >> 8;              // groups of 256 candidates

    // ---- pass 1: branchless top-8 distances for both queries ----
    float a0 = FLT_MAX, a1 = FLT_MAX, a2 = FLT_MAX, a3 = FLT_MAX,
          a4 = FLT_MAX, a5 = FLT_MAX, a6 = FLT_MAX, a7 = FLT_MAX;
    float b0r = FLT_MAX, b1 = FLT_MAX, b2 = FLT_MAX, b3 = FLT_MAX,
          b4 = FLT_MAX, b5 = FLT_MAX, b6 = FLT_MAX, b7 = FLT_MAX;
    {
      for (int it = 0; it < F4; ++it) {
        int base = lo_i + (it << 8) + lane;
        #pragma unroll
        for (int q = 0; q < 4; ++q) {
          int i = base + (q << 6);
          float cxv = xs[i], cyv = ys[i], czv = zs[i];
          float dA = dist2(cxv, cyv, czv, ax, ay, az);
          float dB = dist2(cxv, cyv, czv, bx, by, bz);
          INS8V(dA, a0, a1, a2, a3, a4, a5, a6, a7);
          INS8V(dB, b0r, b1, b2, b3, b4, b5, b6, b7);
        }
      }
      for (int base = F4 << 8; base < M; base += 64) {
        int lix = base + lane;
        bool ok = lix < M;
        int i = ok ? (lo_i + lix) : lo_i;
        float cxv = xs[i], cyv = ys[i], czv = zs[i];
        float dA = dist2(cxv, cyv, czv, ax, ay, az);
        float dB = dist2(cxv, cyv, czv, bx, by, bz);
        dA = ok ? dA : FLT_MAX;
        dB = ok ? dB : FLT_MAX;
        INS8V(dA, a0, a1, a2, a3, a4, a5, a6, a7);
        INS8V(dB, b0r, b1, b2, b3, b4, b5, b6, b7);
      }
    }

    // ---- merge: exact 8th-smallest per query ----
    float TA = merge_T(a0, a1, a2, a3, a4, a5, a6, a7, lane);
    float TB = merge_T(b0r, b1, b2, b3, b4, b5, b6, b7, lane);

    // ---- pass 2: collect first-8-by-index with d <= T (order-free downstream;
    //      lowest-index tie policy matches stable top_k) ----
    unsigned long long lt = (1ull << lane) - 1ull;
    int cntA = 0, cntB = 0;
    {
      for (int it = 0; it < F4 && (cntA < KNB || cntB < KNB); ++it) {
        int base = lo_i + (it << 8) + lane;
        int g0 = sA + (it << 8) + lane;
        #pragma unroll
        for (int q = 0; q < 4; ++q) {
          int i = base + (q << 6);
          int gidx = g0 + (q << 6);
          float cxv = xs[i], cyv = ys[i], czv = zs[i];
          float dA = dist2(cxv, cyv, czv, ax, ay, az);
          float dB = dist2(cxv, cyv, czv, bx, by, bz);
          unsigned long long mA = __ballot(dA <= TA);
          if (mA) {
            int slot = cntA + __popcll(mA & lt);
            if ((dA <= TA) && slot < KNB) knn[nA*KNB + slot] = gidx;
            cntA += __popcll(mA);
          }
          unsigned long long mB = __ballot(dB <= TB);
          if (mB) {
            int slot = cntB + __popcll(mB & lt);
            if ((dB <= TB) && slot < KNB) knn[nB*KNB + slot] = gidx;
            cntB += __popcll(mB);
          }
        }
      }
      for (int base = F4 << 8; base < M && (cntA < KNB || cntB < KNB); base += 64) {
        int lix = base + lane;
        bool ok = lix < M;
        int i = ok ? (lo_i + lix) : lo_i;
        float cxv = xs[i], cyv = ys[i], czv = zs[i];
        float dA = dist2(cxv, cyv, czv, ax, ay, az);
        float dB = dist2(cxv, cyv, czv, bx, by, bz);
        int gidx = sA + lix;
        bool wA = ok && (dA <= TA);
        bool wB = ok && (dB <= TB);
        unsigned long long mA = __ballot(wA);
        if (mA) {
          int slot = cntA + __popcll(mA & lt);
          if (wA && slot < KNB) knn[nA*KNB + slot] = gidx;
          cntA += __popcll(mA);
        }
        unsigned long long mB = __ballot(wB);
        if (mB) {
          int slot = cntB + __popcll(mB & lt);
          if (wB && slot < KNB) knn[nB*KNB + slot] = gidx;
          cntB += __popcll(mB);
        }
      }
    }
  } else {
    // rare: graph straddle / window overflow — global exact scan per query
    int sB2 = seg[bB], eB2 = seg[bB + 1];
    knn_global_single(coord, ax, ay, az, sA, eA, lane, knn + (size_t)nA * KNB);
    knn_global_single(coord, bx, by, bz, sB2, eB2, lane, knn + (size_t)nB * KNB);
  }

  // ---- fused layer-0 linear: xl/xr = feat @ Wl0/Wr0 + b for this block's 16 nodes ----
  {
    int cg = t & 63;                 // 64 col-groups of 4 (0..31 -> xl, 32..63 -> xr)
    bool isR = cg >= 32;
    const float* W  = isR ? Wr0 : Wl0;
    const float* bi = isR ? br0 : bl0;
    float* dst      = isR ? xr : xl;
    int wc = (cg & 31) * 4;
    float4 w0 = *(const float4*)(W + 0 * HIDC + wc);
    float4 w1 = *(const float4*)(W + 1 * HIDC + wc);
    float4 w2 = *(const float4*)(W + 2 * HIDC + wc);
    float4 w3 = *(const float4*)(W + 3 * HIDC + wc);
    float4 w4 = *(const float4*)(W + 4 * HIDC + wc);
    float4 w5 = *(const float4*)(W + 5 * HIDC + wc);
    float4 bb = *(const float4*)(bi + wc);
    #pragma unroll
    for (int s2 = 0; s2 < 2; ++s2) {
      int node = n0 + wid * 2 + s2;
      const float* fr = feat + (size_t)node * 6;
      float f0 = fr[0], f1 = fr[1], f2 = fr[2], f3 = fr[3], f4 = fr[4], f5 = fr[5];
      float4 acc = make_float4(0.f, 0.f, 0.f, 0.f);
      acc.x = fmaf(f0, w0.x, acc.x); acc.y = fmaf(f0, w0.y, acc.y);
      acc.z = fmaf(f0, w0.z, acc.z); acc.w = fmaf(f0, w0.w, acc.w);
      acc.x = fmaf(f1, w1.x, acc.x); acc.y = fmaf(f1, w1.y, acc.y);
      acc.z = fmaf(f1, w1.z, acc.z); acc.w = fmaf(f1, w1.w, acc.w);
      acc.x = fmaf(f2, w2.x, acc.x); acc.y = fmaf(f2, w2.y, acc.y);
      acc.z = fmaf(f2, w2.z, acc.z); acc.w = fmaf(f2, w2.w, acc.w);
      acc.x = fmaf(f3, w3.x, acc.x); acc.y = fmaf(f3, w3.y, acc.y);
      acc.z = fmaf(f3, w3.z, acc.z); acc.w = fmaf(f3, w3.w, acc.w);
      acc.x = fmaf(f4, w4.x, acc.x); acc.y = fmaf(f4, w4.y, acc.y);
      acc.z = fmaf(f4, w4.z, acc.z); acc.w = fmaf(f4, w4.w, acc.w);
      acc.x = fmaf(f5, w5.x, acc.x); acc.y = fmaf(f5, w5.y, acc.y);
      acc.z = fmaf(f5, w5.z, acc.z); acc.w = fmaf(f5, w5.w, acc.w);
      float4 o;
      o.x = acc.x + bb.x; o.y = acc.y + bb.y;
      o.z = acc.z + bb.z; o.w = acc.w + bb.w;
      *(float4*)(dst + (size_t)node * HIDC + wc) = o;
    }
  }
}

// ---------------- xl = x@Wl + bl ; xr = x@Wr + br  (16-node tiles) ----------
__global__ __launch_bounds__(256) void lin2_kernel(
    const float* __restrict__ x,
    const float* __restrict__ Wl, const float* __restrict__ bl,
    const float* __restrict__ Wr, const float* __restrict__ br,
    float* __restrict__ xl, float* __restrict__ xr) {
  __shared__ float xshm[16 * HIDC];
  int t = threadIdx.x;
  int node0 = blockIdx.x * 16;
  for (int i = t; i < 16 * HIDC; i += 256) xshm[i] = x[node0 * HIDC + i];
  __syncthreads();
  int cg = t & 63;        // 64 col-groups x 4 cols = 256 combined cols
  int ng = t >> 6;        // 4 node-groups x 4 nodes
  int c0 = cg * 4;
  bool isR = (c0 >= HIDC);
  const float* W    = isR ? Wr : Wl;
  const float* bias = isR ? br : bl;
  float* dst        = isR ? xr : xl;
  int wc = isR ? (c0 - HIDC) : c0;

  float4 acc[4];
  #pragma unroll
  for (int nn = 0; nn < 4; ++nn) acc[nn] = make_float4(0.f, 0.f, 0.f, 0.f);

  for (int k0 = 0; k0 < HIDC; k0 += 4) {
    float4 xv[4];
    #pragma unroll
    for (int nn = 0; nn < 4; ++nn)
      xv[nn] = *(const float4*)&xshm[(ng * 4 + nn) * HIDC + k0];  // uniform-addr broadcast
    #pragma unroll
    for (int q = 0; q < 4; ++q) {
      float4 w = *(const float4*)(W + (size_t)(k0 + q) * HIDC + wc);
      #pragma unroll
      for (int nn = 0; nn < 4; ++nn) {
        float xq = (q == 0) ? xv[nn].x : (q == 1) ? xv[nn].y : (q == 2) ? xv[nn].z : xv[nn].w;
        acc[nn].x = fmaf(xq, w.x, acc[nn].x);
        acc[nn].y = fmaf(xq, w.y, acc[nn].y);
        acc[nn].z = fmaf(xq, w.z, acc[nn].z);
        acc[nn].w = fmaf(xq, w.w, acc[nn].w);
      }
    }
  }
  float4 b4 = *(const float4*)(bias + wc);
  #pragma unroll
  for (int nn = 0; nn < 4; ++nn) {
    int node = node0 + ng * 4 + nn;
    float4 o;
    o.x = acc[nn].x + b4.x; o.y = acc[nn].y + b4.y;
    o.z = acc[nn].z + b4.z; o.w = acc[nn].w + b4.w;
    *(float4*)(dst + (size_t)node * HIDC + wc) = o;
  }
}

// -------- GATv2 attention + aggregate + bias + relu (wave per node), optional fused final --
template<bool FINAL>
__global__ __launch_bounds__(256) void gat_attn_kernel(
    const float* __restrict__ xl, const float* __restrict__ xr,
    const int* __restrict__ knn, const float* __restrict__ att,
    const float* __restrict__ bias, float* __restrict__ xout,
    const float* __restrict__ Wf, const float* __restrict__ bf,
    float* __restrict__ out) {
  int wid = threadIdx.x >> 6;
  int lane = threadIdx.x & 63;
  int n = blockIdx.x * 4 + wid;
  int c0 = 2 * lane, c1 = 2 * lane + 1;
  float2 xr2 = *(const float2*)(xr + (size_t)n * HIDC + c0);
  float2 a2  = *(const float2*)(att + c0);
  int myj = (lane < KNB) ? knn[n * KNB + lane] : 0;
  float g0[8], g1[8], lg[8];
  #pragma unroll
  for (int k = 0; k < 8; ++k) {
    int j = __builtin_amdgcn_readlane(myj, k);
    float2 g = *(const float2*)(xl + (size_t)j * HIDC + c0);
    g0[k] = g.x; g1[k] = g.y;
    float e0 = g.x + xr2.x; e0 = (e0 > 0.f) ? e0 : 0.2f * e0;
    float e1 = g.y + xr2.y; e1 = (e1 > 0.f) ? e1 : 0.2f * e1;
    lg[k] = wave_sum(e0 * a2.x + e1 * a2.y);
  }
  float mx = lg[0];
  #pragma unroll
  for (int k = 1; k < 8; ++k) mx = fmaxf(mx, lg[k]);
  float ssum = 0.f, w[8];
  #pragma unroll
  for (int k = 0; k < 8; ++k) { w[k] = __expf(lg[k] - mx); ssum += w[k]; }
  float inv = 1.f / ssum;
  float o0 = 0.f, o1 = 0.f;
  #pragma unroll
  for (int k = 0; k < 8; ++k) { o0 += w[k] * g0[k]; o1 += w[k] * g1[k]; }
  o0 = fmaxf(fmaf(o0, inv, bias[c0]), 0.f);
  o1 = fmaxf(fmaf(o1, inv, bias[c1]), 0.f);
  if (!FINAL) {
    float2 o; o.x = o0; o.y = o1;
    *(float2*)(xout + (size_t)n * HIDC + c0) = o;
  } else {
    #pragma unroll
    for (int cls = 0; cls < 3; ++cls) {
      float p = wave_sum(o0 * Wf[c0 * 3 + cls] + o1 * Wf[c1 * 3 + cls]);
      if (lane == 0) out[n * 3 + cls] = p + bf[cls];
    }
  }
}

extern "C" void kernel_launch(void* const* d_in, const int* in_sizes, int n_in,
                              void* d_out, int out_size, void* d_ws, size_t ws_size,
                              hipStream_t stream) {
  const float* coord = (const float*)d_in[0];
  const float* feat  = (const float*)d_in[1];
  const int*   batch = (const int*)d_in[2];
  const float* Wl0 = (const float*)d_in[3];
  const float* bl0 = (const float*)d_in[4];
  const float* Wr0 = (const float*)d_in[5];
  const float* br0 = (const float*)d_in[6];
  const float* att0  = (const float*)d_in[7];
  const float* bias0 = (const float*)d_in[8];
  const float* Wl1 = (const float*)d_in[9];
  const float* bl1 = (const float*)d_in[10];
  const float* Wr1 = (const float*)d_in[11];
  const float* br1 = (const float*)d_in[12];
  const float* att1  = (const float*)d_in[13];
  const float* bias1 = (const float*)d_in[14];
  const float* Wl2 = (const float*)d_in[15];
  const float* bl2 = (const float*)d_in[16];
  const float* Wr2 = (const float*)d_in[17];
  const float* br2 = (const float*)d_in[18];
  const float* att2  = (const float*)d_in[19];
  const float* bias2 = (const float*)d_in[20];
  const float* Wf = (const float*)d_in[21];
  const float* bf = (const float*)d_in[22];
  float* out = (float*)d_out;

  char* ws = (char*)d_ws;
  int*   knn = (int*)ws;                                   // 512 KB
  float* xl  = (float*)(ws + (512 << 10));                 // 8 MB
  float* xr  = xl + (size_t)NNODES * HIDC;                 // 8 MB
  float* xb0 = xr + (size_t)NNODES * HIDC;                 // 8 MB
  float* xb1 = xb0 + (size_t)NNODES * HIDC;                // 8 MB
  int*   seg = (int*)xb1;  // 9 ints; xb1 not live until gat1 writes it

  seg_kernel<<<1, 16, 0, stream>>>(batch, seg);
  knnlin_kernel<<<NNODES / 16, 512, 0, stream>>>(coord, batch, feat,
                                                 Wl0, bl0, Wr0, br0, seg, knn, xl, xr);
  gat_attn_kernel<false><<<NNODES / 4, 256, 0, stream>>>(xl, xr, knn, att0, bias0, xb0,
                                                         nullptr, nullptr, nullptr);

  lin2_kernel<<<NNODES / 16, 256, 0, stream>>>(xb0, Wl1, bl1, Wr1, br1, xl, xr);
  gat_attn_kernel<false><<<NNODES / 4, 256, 0, stream>>>(xl, xr, knn, att1, bias1, xb1,
                                                         nullptr, nullptr, nullptr);

  lin2_kernel<<<NNODES / 16, 256, 0, stream>>>(xb1, Wl2, bl2, Wr2, br2, xl, xr);
  gat_attn_kernel<true><<<NNODES / 4, 256, 0, stream>>>(xl, xr, knn, att2, bias2, nullptr,
                                                        Wf, bf, out);
}